// Round 5
// baseline (61.890 us; speedup 1.0000x reference)
//
#include <hip/hip_runtime.h>
#include <math.h>

// loss = sum_q softmax-weighted avg of w_k, per ragged segment.
//   s2_qk = 1.25*log2(e) * dot(t1[q], t1[k])   (exp2 domain; 10x K + 1/8 folded)
//   w_k   = 10 * rowsum(t1[k])
// seg0: q [0,4096),     k [0,2048)
// seg1: q [4096,10240), k [2048,10240)
// Scores: bf16 hi/lo split MFMA (hh + hl + lh), swapped operands (S^T = K*Q^T).
// K pre-split by prep kernel -> Ksplit[T][128] bf16 (cols 0-63 hi, 64-127 lo),
// staged via global_load_lds with pre-swizzled source (linear LDS dest).
// m seeded with self-score => whole tiles skip softmax via __all().
// R5: 8-wave blocks (q-tile 128), k-chunk 512 -> 896 blocks, ~24 waves/CU.

#define T_ROWS 10240
#define DHEAD  64
#define SCALE2 1.80336880f   // 1.25 * log2(e)
#define SKIP_THR 35.0f
#define CHUNK  512
#define NT     8             // k-tiles of 32 per k-sub (256 rows / 32)

typedef __bf16 bf16x8 __attribute__((ext_vector_type(8)));
typedef float  f32x16 __attribute__((ext_vector_type(16)));
typedef float  f32x4v __attribute__((ext_vector_type(4)));

// hardware exp2: v_exp_f32 computes 2^x; exp2(-inf) = 0
__device__ __forceinline__ float ex2(float x) {
    return __builtin_amdgcn_exp2f(x);
}

// ---------------------------------------------------------------- prep
// Ksplit hi/lo, w = 10*rowsum, selfs = SCALE2*sumsq. 32 rows/block, 8 thr/row.
__global__ __launch_bounds__(256)
void prep_kernel(const float* __restrict__ base, __bf16* __restrict__ ksplit,
                 float* __restrict__ w, float* __restrict__ selfs) {
    int tid = threadIdx.x;
    int row = blockIdx.x * 32 + (tid >> 3);
    int c0  = (tid & 7) << 3;
    const float* p = base + row * DHEAD + c0;
    f32x4v a = *(const f32x4v*)p;
    f32x4v b = *(const f32x4v*)(p + 4);

    float sum = ((a[0] + a[1]) + (a[2] + a[3])) + ((b[0] + b[1]) + (b[2] + b[3]));
    float sq = a[0] * a[0];
    sq = fmaf(a[1], a[1], sq); sq = fmaf(a[2], a[2], sq); sq = fmaf(a[3], a[3], sq);
    sq = fmaf(b[0], b[0], sq); sq = fmaf(b[1], b[1], sq);
    sq = fmaf(b[2], b[2], sq); sq = fmaf(b[3], b[3], sq);
    #pragma unroll
    for (int off = 1; off < 8; off <<= 1) {
        sum += __shfl_xor(sum, off);
        sq  += __shfl_xor(sq, off);
    }
    if ((tid & 7) == 0) { w[row] = 10.0f * sum; selfs[row] = SCALE2 * sq; }

    bf16x8 h, l;
    #pragma unroll
    for (int j = 0; j < 4; ++j) {
        __bf16 h0 = (__bf16)a[j];
        h[j] = h0; l[j] = (__bf16)(a[j] - (float)h0);
        __bf16 h1 = (__bf16)b[j];
        h[j + 4] = h1; l[j + 4] = (__bf16)(b[j] - (float)h1);
    }
    *(bf16x8*)(ksplit + (size_t)row * 128 + c0)      = h;
    *(bf16x8*)(ksplit + (size_t)row * 128 + 64 + c0) = l;
}

// ---------------------------------------------------------------- attn
// Block: 8 waves (512 thr). 128 q x 512 k chunk.
// wave: qs = wid&3 (32 q rows), ks = wid>>2 (256 k rows, 8 tiles of 32).
__global__ __launch_bounds__(512, 6)
void attn_mfma_kernel(const float* __restrict__ base,
                      const __bf16* __restrict__ ksplit,
                      const float* __restrict__ w,
                      const float* __restrict__ selfs,
                      float* __restrict__ part_out) {
    // KS[buf][ksub]: 32 rows x 128 bf16 (hi|lo), granule-swizzled by row&7
    __shared__ __align__(16) __bf16 KS[2][2][32 * 128];
    __shared__ __align__(16) float  Ws[CHUNK];
    __shared__ float Mg[128][2][3];

    const int tid   = threadIdx.x;
    const int wid   = tid >> 6;
    const int lane  = tid & 63;
    const int l31   = lane & 31;
    const int lhalf = lane >> 5;

    // grid: seg0 = 32 qtiles x 4 chunks (bid<128); seg1 = 48 x 16 (bid>=128)
    int bid = blockIdx.x, qbase, kbase, chunk;
    if (bid < 128) {
        qbase = (bid >> 2) * 128; chunk = bid & 3; kbase = chunk * CHUNK;
    } else {
        int idx = bid - 128;
        qbase = 4096 + (idx >> 4) * 128;
        chunk = idx & 15;
        kbase = 2048 + chunk * CHUNK;
    }
    const int qs = wid & 3, ks = wid >> 2;

    // stage w chunk (512 f32, one per thread)
    Ws[tid] = w[kbase + tid];

    // Q fragments (scaled by SCALE2, hi/lo split in regs)
    bf16x8 qhi[4], qlo[4];
    const int qrow = qbase + qs * 32 + l31;
    {
        const float* qptr = base + (size_t)qrow * DHEAD + lhalf * 8;
        #pragma unroll
        for (int st = 0; st < 4; ++st) {
            f32x4v a = *(const f32x4v*)(qptr + st * 16);
            f32x4v b = *(const f32x4v*)(qptr + st * 16 + 4);
            #pragma unroll
            for (int j = 0; j < 4; ++j) {
                float v0 = a[j] * SCALE2, v1 = b[j] * SCALE2;
                __bf16 h0 = (__bf16)v0, h1 = (__bf16)v1;
                qhi[st][j]     = h0;
                qhi[st][j + 4] = h1;
                qlo[st][j]     = (__bf16)(v0 - (float)h0);
                qlo[st][j + 4] = (__bf16)(v1 - (float)h1);
            }
        }
    }

    // m seeded with self-score (valid upper bound whenever self in segment's
    // k-range; chunks without self may end (m,0,0) — finalize merge handles).
    float m = (qbase < 4096 && qrow >= 2048) ? -INFINITY : selfs[qrow];
    float Z = 0.f, Nm = 0.f;

    // staging: 16 x 1KB wave-issues per tile pair; this wave owns fi = wid*2+ii.
    // LDS linear dest; source granule pre-swizzled: slot gsl <- granule gsl^(row&7).
    const __bf16* gsrc[2];
    int ksub_[2], ibuf_[2];
    #pragma unroll
    for (int ii = 0; ii < 2; ++ii) {
        int fi   = wid * 2 + ii;
        int ksub = fi >> 3, ibuf = fi & 7;
        int row  = ibuf * 4 + (lane >> 4);
        int gsl  = lane & 15;
        int g    = gsl ^ (row & 7);
        gsrc[ii] = ksplit + (size_t)(kbase + ksub * 256 + row) * 128 + g * 8;
        ksub_[ii] = ksub; ibuf_[ii] = ibuf;
    }
    auto stage = [&](int buf, int t) {
        #pragma unroll
        for (int ii = 0; ii < 2; ++ii) {
            __builtin_amdgcn_global_load_lds(
                (const void*)(gsrc[ii] + (size_t)t * (32 * 128)),
                (void*)&KS[buf][ksub_[ii]][ibuf_[ii] * 512],
                16, 0, 0);
        }
    };

    stage(0, 0);
    __syncthreads();   // barrier drains vmcnt(0): tile 0 staged (and Ws visible)

    for (int t = 0; t < NT; ++t) {
        const int cur = t & 1;
        if (t + 1 < NT) stage(cur ^ 1, t + 1);   // issue early; drained at barrier

        // ---- scores: 12 MFMA (4 K-steps x {hh, hl, lh}) ----
        const __bf16* kp = &KS[cur][ks][0];
        f32x16 acc0, acc1;
        #pragma unroll
        for (int r = 0; r < 16; ++r) { acc0[r] = 0.f; acc1[r] = 0.f; }
        __builtin_amdgcn_s_setprio(1);
        #pragma unroll
        for (int st = 0; st < 4; ++st) {
            const int off = l31 * 128 + (((st * 2 + lhalf) ^ (l31 & 7)) << 3);
            bf16x8 kh = *(const bf16x8*)(kp + off);
            bf16x8 kl = *(const bf16x8*)(kp + off + 64);
            acc0 = __builtin_amdgcn_mfma_f32_32x32x16_bf16(kh, qhi[st], acc0, 0, 0, 0);
            acc1 = __builtin_amdgcn_mfma_f32_32x32x16_bf16(kh, qlo[st], acc1, 0, 0, 0);
            acc1 = __builtin_amdgcn_mfma_f32_32x32x16_bf16(kl, qhi[st], acc1, 0, 0, 0);
        }
        __builtin_amdgcn_s_setprio(0);

        // ---- cheap skip test on acc0 (|acc1| << 1; margin inside SKIP_THR) ----
        float h0 = fmaxf(fmaxf(acc0[0],  acc0[1]),  fmaxf(acc0[2],  acc0[3]));
        float h1 = fmaxf(fmaxf(acc0[4],  acc0[5]),  fmaxf(acc0[6],  acc0[7]));
        float h2 = fmaxf(fmaxf(acc0[8],  acc0[9]),  fmaxf(acc0[10], acc0[11]));
        float h3 = fmaxf(fmaxf(acc0[12], acc0[13]), fmaxf(acc0[14], acc0[15]));
        float hmax = fmaxf(fmaxf(h0, h1), fmaxf(h2, h3));

        if (!__all(hmax <= m - SKIP_THR)) {
            float s_[16];
            #pragma unroll
            for (int r = 0; r < 16; ++r) s_[r] = acc0[r] + acc1[r];
            float mx0 = fmaxf(fmaxf(s_[0], s_[4]), fmaxf(s_[8],  s_[12]));
            float mx1 = fmaxf(fmaxf(s_[1], s_[5]), fmaxf(s_[9],  s_[13]));
            float mx2 = fmaxf(fmaxf(s_[2], s_[6]), fmaxf(s_[10], s_[14]));
            float mx3 = fmaxf(fmaxf(s_[3], s_[7]), fmaxf(s_[11], s_[15]));
            float tmax = fmaxf(fmaxf(mx0, mx1), fmaxf(mx2, mx3));
            float mn = fmaxf(m, tmax);
            float sc = ex2(m - mn);              // exp2(-inf)=0 first time

            const int wb = ks * 256 + t * 32 + 4 * lhalf;
            f32x4v wv[4];
            #pragma unroll
            for (int g = 0; g < 4; ++g)
                wv[g] = *(const f32x4v*)&Ws[wb + 8 * g];

            float z0 = 0.f, z1 = 0.f, z2 = 0.f, z3 = 0.f;
            float n0 = 0.f, n1 = 0.f, n2 = 0.f, n3 = 0.f;
            #pragma unroll
            for (int g = 0; g < 4; ++g) {
                float e0 = ex2(s_[g * 4]     - mn);
                float e1 = ex2(s_[g * 4 + 1] - mn);
                float e2 = ex2(s_[g * 4 + 2] - mn);
                float e3 = ex2(s_[g * 4 + 3] - mn);
                z0 += e0; z1 += e1; z2 += e2; z3 += e3;
                n0 = fmaf(e0, wv[g][0], n0);
                n1 = fmaf(e1, wv[g][1], n1);
                n2 = fmaf(e2, wv[g][2], n2);
                n3 = fmaf(e3, wv[g][3], n3);
            }
            Z  = fmaf(Z,  sc, (z0 + z1) + (z2 + z3));
            Nm = fmaf(Nm, sc, (n0 + n1) + (n2 + n3));
            m  = mn;
        }
        __syncthreads();   // cur reads done by all; next-tile staging drained
    }

    // ---- combine lane l with l^32 (complementary k rows) ----
    {
        float mo = __shfl(m,  lane ^ 32);
        float Zo = __shfl(Z,  lane ^ 32);
        float No = __shfl(Nm, lane ^ 32);
        float mn = fmaxf(m, mo);
        float ea = ex2(m - mn), eb = ex2(mo - mn);
        float Zc = Z * ea + Zo * eb;
        float Nc = Nm * ea + No * eb;
        if (lhalf == 0) {
            Mg[qs * 32 + l31][ks][0] = mn;
            Mg[qs * 32 + l31][ks][1] = Zc;
            Mg[qs * 32 + l31][ks][2] = Nc;
        }
    }
    __syncthreads();

    // ---- combine the two k-subs, write chunk partial ----
    if (tid < 128) {
        float ma = Mg[tid][0][0], Za = Mg[tid][0][1], Na = Mg[tid][0][2];
        float mb = Mg[tid][1][0], Zb = Mg[tid][1][1], Nb = Mg[tid][1][2];
        float mn = fmaxf(ma, mb);
        float ea = ex2(ma - mn), eb = ex2(mb - mn);
        float* dst = &part_out[((qbase + tid) * 16 + chunk) * 3];
        dst[0] = mn;
        dst[1] = Za * ea + Zb * eb;
        dst[2] = Na * ea + Nb * eb;
    }
}

// ---------------------------------------------------------------- finalize
__global__ void finalize_kernel(const float* __restrict__ part,
                                float* __restrict__ out) {
    __shared__ float red[256];
    int gq = blockIdx.x * 256 + threadIdx.x;
    float contrib = 0.f;
    if (gq < T_ROWS) {
        int nch = (gq < 4096) ? 4 : 16;
        float mm = -INFINITY, zz = 0.f, nn = 0.f;
        for (int c = 0; c < nch; ++c) {
            const float* p = &part[(gq * 16 + c) * 3];
            float mc = p[0], zc = p[1], nc = p[2];
            float mn = fmaxf(mm, mc);
            float s0 = ex2(mm - mn), s1 = ex2(mc - mn);
            zz = zz * s0 + zc * s1;
            nn = nn * s0 + nc * s1;
            mm = mn;
        }
        contrib = nn / zz;
    }
    red[threadIdx.x] = contrib;
    __syncthreads();
    #pragma unroll
    for (int s = 128; s > 0; s >>= 1) {
        if (threadIdx.x < s) red[threadIdx.x] += red[threadIdx.x + s];
        __syncthreads();
    }
    if (threadIdx.x == 0) atomicAdd(out, red[0]);
}

// ----------------------------------------------------------------- launch
extern "C" void kernel_launch(void* const* d_in, const int* in_sizes, int n_in,
                              void* d_out, int out_size, void* d_ws, size_t ws_size,
                              hipStream_t stream) {
    const float* base = (const float*)d_in[0];
    float* out = (float*)d_out;
    float* ws  = (float*)d_ws;

    float*  w      = ws;                        // 10240 f32
    float*  selfs  = ws + T_ROWS;               // 10240 f32
    float*  part   = ws + 2 * T_ROWS;           // 10240*16*3 f32
    __bf16* ksplit = (__bf16*)(ws + 2 * T_ROWS + T_ROWS * 48);  // 10240*128 bf16

    (void)hipMemsetAsync(d_out, 0, sizeof(float), stream);

    prep_kernel<<<T_ROWS / 32, 256, 0, stream>>>(base, ksplit, w, selfs);
    // seg0: 32 qtiles x 4 chunks = 128; seg1: 48 x 16 = 768 -> 896 blocks
    attn_mfma_kernel<<<896, 512, 0, stream>>>(base, ksplit, w, selfs, part);
    finalize_kernel<<<T_ROWS / 256, 256, 0, stream>>>(part, out);
}

// Round 6
// 45.138 us; speedup vs baseline: 1.3711x; 1.3711x over previous
//
#include <hip/hip_runtime.h>
#include <math.h>

// loss = sum_q softmax-weighted avg of w_k, per ragged segment.
//   s2_qk = 1.25*log2(e) * dot(t1[q], t1[k])   (exp2 domain; 10x K + 1/8 folded)
//   w_k   = 10 * rowsum(t1[k])
// seg0: q [0,4096),     k [0,2048)
// seg1: q [4096,10240), k [2048,10240)
// Scores: bf16 hi/lo split MFMA (hh + hl + lh), swapped operands (S^T = K*Q^T).
// K pre-split by prep kernel -> Ksplit[T][128] bf16 (hi | lo), staged via
// global_load_lds (pre-swizzled source, linear LDS dest).
// R6: 3-buffer pipeline, counted s_waitcnt vmcnt(2) + raw s_barrier (T3/T4):
// next-next tile's loads stay in flight across the barrier - no vmcnt(0) drain
// in the main loop. 8-wave blocks, q-tile 128, CHUNK 1024, 448 blocks.

#define T_ROWS 10240
#define DHEAD  64
#define SCALE2 1.80336880f   // 1.25 * log2(e)
#define SKIP_THR 35.0f
#define CHUNK  1024
#define NT     16            // 32-row k-tiles per ksub (512/32)

typedef __bf16 bf16x8 __attribute__((ext_vector_type(8)));
typedef float  f32x16 __attribute__((ext_vector_type(16)));
typedef float  f32x4v __attribute__((ext_vector_type(4)));

// hardware exp2: v_exp_f32 computes 2^x; exp2(-inf) = 0
__device__ __forceinline__ float ex2(float x) {
    return __builtin_amdgcn_exp2f(x);
}

// ---------------------------------------------------------------- prep
// Ksplit hi/lo, w = 10*rowsum, selfs = SCALE2*sumsq. 32 rows/block, 8 thr/row.
__global__ __launch_bounds__(256)
void prep_kernel(const float* __restrict__ base, __bf16* __restrict__ ksplit,
                 float* __restrict__ w, float* __restrict__ selfs) {
    int tid = threadIdx.x;
    int row = blockIdx.x * 32 + (tid >> 3);
    int c0  = (tid & 7) << 3;
    const float* p = base + row * DHEAD + c0;
    f32x4v a = *(const f32x4v*)p;
    f32x4v b = *(const f32x4v*)(p + 4);

    float sum = ((a[0] + a[1]) + (a[2] + a[3])) + ((b[0] + b[1]) + (b[2] + b[3]));
    float sq = a[0] * a[0];
    sq = fmaf(a[1], a[1], sq); sq = fmaf(a[2], a[2], sq); sq = fmaf(a[3], a[3], sq);
    sq = fmaf(b[0], b[0], sq); sq = fmaf(b[1], b[1], sq);
    sq = fmaf(b[2], b[2], sq); sq = fmaf(b[3], b[3], sq);
    #pragma unroll
    for (int off = 1; off < 8; off <<= 1) {
        sum += __shfl_xor(sum, off);
        sq  += __shfl_xor(sq, off);
    }
    if ((tid & 7) == 0) { w[row] = 10.0f * sum; selfs[row] = SCALE2 * sq; }

    bf16x8 h, l;
    #pragma unroll
    for (int j = 0; j < 4; ++j) {
        __bf16 h0 = (__bf16)a[j];
        h[j] = h0; l[j] = (__bf16)(a[j] - (float)h0);
        __bf16 h1 = (__bf16)b[j];
        h[j + 4] = h1; l[j + 4] = (__bf16)(b[j] - (float)h1);
    }
    *(bf16x8*)(ksplit + (size_t)row * 128 + c0)      = h;
    *(bf16x8*)(ksplit + (size_t)row * 128 + 64 + c0) = l;
}

// ---------------------------------------------------------------- attn
// Block: 8 waves (512 thr). 128 q x 1024 k chunk.
// wave: qs = wid&3 (32 q rows), ks = wid>>2 (512 k rows = 16 tiles of 32).
__global__ __launch_bounds__(512, 4)
void attn_mfma_kernel(const float* __restrict__ base,
                      const __bf16* __restrict__ ksplit,
                      const float* __restrict__ w,
                      const float* __restrict__ selfs,
                      float* __restrict__ part_out) {
    // KS[buf][ksub]: 32 rows x 128 bf16 (hi|lo), granule-swizzled by row&7
    __shared__ __align__(16) __bf16 KS[3][2][32 * 128];
    __shared__ __align__(16) float  Ws[CHUNK];
    __shared__ float Mg[128][2][3];

    const int tid   = threadIdx.x;
    const int wid   = tid >> 6;
    const int lane  = tid & 63;
    const int l31   = lane & 31;
    const int lhalf = lane >> 5;

    // bijective XCD swizzle: 448 = 8 * 56; seg1 blocks sharing a k-chunk
    // (bid stride 8) land on the same XCD -> chunk-local L2.
    const int bid = ((int)blockIdx.x & 7) * 56 + ((int)blockIdx.x >> 3);

    int qbase, kbase, chunk;
    if (bid < 64) {            // seg0: 32 qtiles x 2 chunks
        qbase = (bid >> 1) * 128; chunk = bid & 1; kbase = chunk * CHUNK;
    } else {                   // seg1: 48 qtiles x 8 chunks
        int idx = bid - 64;
        qbase = 4096 + (idx >> 3) * 128;
        chunk = idx & 7;
        kbase = 2048 + chunk * CHUNK;
    }
    const int qs = wid & 3, ks = wid >> 2;

    // staging geometry: 16 x 1KB wave-issues per tile; this wave owns fi=wid*2+ii.
    // LDS linear dest; source granule pre-swizzled: slot gsl <- granule gsl^(row&7).
    const __bf16* gsrc[2];
    int ksub_[2], ibuf_[2];
    #pragma unroll
    for (int ii = 0; ii < 2; ++ii) {
        int fi   = wid * 2 + ii;
        int ksub = fi >> 3, ibuf = fi & 7;
        int row  = ibuf * 4 + (lane >> 4);
        int g    = (lane & 15) ^ (row & 7);
        gsrc[ii] = ksplit + (size_t)(kbase + ksub * 512 + row) * 128 + g * 8;
        ksub_[ii] = ksub; ibuf_[ii] = ibuf;
    }
    auto stage = [&](int buf, int t) {
        #pragma unroll
        for (int ii = 0; ii < 2; ++ii) {
            __builtin_amdgcn_global_load_lds(
                (const void*)(gsrc[ii] + (size_t)t * (32 * 128)),
                (void*)&KS[buf][ksub_[ii]][ibuf_[ii] * 512],
                16, 0, 0);
        }
    };

    // prologue: issue tiles 0 and 1 immediately (flight overlaps Q-prep)
    stage(0, 0);
    stage(1, 1);

    // stage w chunk (1024 f32, 2 per thread)
    Ws[tid]       = w[kbase + tid];
    Ws[tid + 512] = w[kbase + tid + 512];

    // Q fragments (scaled by SCALE2, hi/lo split in regs)
    bf16x8 qhi[4], qlo[4];
    const int qrow = qbase + qs * 32 + l31;
    {
        const float* qptr = base + (size_t)qrow * DHEAD + lhalf * 8;
        #pragma unroll
        for (int st = 0; st < 4; ++st) {
            f32x4v a = *(const f32x4v*)(qptr + st * 16);
            f32x4v b = *(const f32x4v*)(qptr + st * 16 + 4);
            #pragma unroll
            for (int j = 0; j < 4; ++j) {
                float v0 = a[j] * SCALE2, v1 = b[j] * SCALE2;
                __bf16 h0 = (__bf16)v0, h1 = (__bf16)v1;
                qhi[st][j]     = h0;
                qhi[st][j + 4] = h1;
                qlo[st][j]     = (__bf16)(v0 - (float)h0);
                qlo[st][j + 4] = (__bf16)(v1 - (float)h1);
            }
        }
    }

    // m seeded with self-score when row q is in this segment's k-range
    float m = (qbase < 4096 && qrow >= 2048) ? -INFINITY : selfs[qrow];
    float Z = 0.f, Nm = 0.f;

    // full drain ONCE (Q/w loads + tiles 0,1); loop never drains vmcnt to 0
    __syncthreads();

    int cur = 0, tgt = 2;
    for (int t = 0; t < NT; ++t) {
        const bool pf = (t + 2 < NT);
        if (pf) stage(tgt, t + 2);     // stays in flight across the barrier

        // ---- scores: 12 MFMA (4 K-steps x {hh, hl, lh}) ----
        const __bf16* kp = &KS[cur][ks][0];
        f32x16 acc0, acc1;
        #pragma unroll
        for (int r = 0; r < 16; ++r) { acc0[r] = 0.f; acc1[r] = 0.f; }
        __builtin_amdgcn_s_setprio(1);
        #pragma unroll
        for (int st = 0; st < 4; ++st) {
            const int off = l31 * 128 + (((st * 2 + lhalf) ^ (l31 & 7)) << 3);
            bf16x8 kh = *(const bf16x8*)(kp + off);
            bf16x8 kl = *(const bf16x8*)(kp + off + 64);
            acc0 = __builtin_amdgcn_mfma_f32_32x32x16_bf16(kh, qhi[st], acc0, 0, 0, 0);
            acc1 = __builtin_amdgcn_mfma_f32_32x32x16_bf16(kh, qlo[st], acc1, 0, 0, 0);
            acc1 = __builtin_amdgcn_mfma_f32_32x32x16_bf16(kl, qhi[st], acc1, 0, 0, 0);
        }
        __builtin_amdgcn_s_setprio(0);

        // ---- cheap skip test on acc0 (|acc1| << 1; margin inside SKIP_THR) ----
        float h0 = fmaxf(fmaxf(acc0[0],  acc0[1]),  fmaxf(acc0[2],  acc0[3]));
        float h1 = fmaxf(fmaxf(acc0[4],  acc0[5]),  fmaxf(acc0[6],  acc0[7]));
        float h2 = fmaxf(fmaxf(acc0[8],  acc0[9]),  fmaxf(acc0[10], acc0[11]));
        float h3 = fmaxf(fmaxf(acc0[12], acc0[13]), fmaxf(acc0[14], acc0[15]));
        float hmax = fmaxf(fmaxf(h0, h1), fmaxf(h2, h3));

        if (!__all(hmax <= m - SKIP_THR)) {
            float s_[16];
            #pragma unroll
            for (int r = 0; r < 16; ++r) s_[r] = acc0[r] + acc1[r];
            float mx0 = fmaxf(fmaxf(s_[0], s_[4]), fmaxf(s_[8],  s_[12]));
            float mx1 = fmaxf(fmaxf(s_[1], s_[5]), fmaxf(s_[9],  s_[13]));
            float mx2 = fmaxf(fmaxf(s_[2], s_[6]), fmaxf(s_[10], s_[14]));
            float mx3 = fmaxf(fmaxf(s_[3], s_[7]), fmaxf(s_[11], s_[15]));
            float tmax = fmaxf(fmaxf(mx0, mx1), fmaxf(mx2, mx3));
            float mn = fmaxf(m, tmax);
            float sc = ex2(m - mn);              // exp2(-inf)=0 first time

            const int wb = ks * 512 + t * 32 + 4 * lhalf;
            f32x4v wv[4];
            #pragma unroll
            for (int g = 0; g < 4; ++g)
                wv[g] = *(const f32x4v*)&Ws[wb + 8 * g];

            float z0 = 0.f, z1 = 0.f, z2 = 0.f, z3 = 0.f;
            float n0 = 0.f, n1 = 0.f, n2 = 0.f, n3 = 0.f;
            #pragma unroll
            for (int g = 0; g < 4; ++g) {
                float e0 = ex2(s_[g * 4]     - mn);
                float e1 = ex2(s_[g * 4 + 1] - mn);
                float e2 = ex2(s_[g * 4 + 2] - mn);
                float e3 = ex2(s_[g * 4 + 3] - mn);
                z0 += e0; z1 += e1; z2 += e2; z3 += e3;
                n0 = fmaf(e0, wv[g][0], n0);
                n1 = fmaf(e1, wv[g][1], n1);
                n2 = fmaf(e2, wv[g][2], n2);
                n3 = fmaf(e3, wv[g][3], n3);
            }
            Z  = fmaf(Z,  sc, (z0 + z1) + (z2 + z3));
            Nm = fmaf(Nm, sc, (n0 + n1) + (n2 + n3));
            m  = mn;
        }

        // counted wait: t+1's loads landed; t+2's stay in flight (T4)
        if (pf) asm volatile("s_waitcnt vmcnt(2)" ::: "memory");
        else    asm volatile("s_waitcnt vmcnt(0)" ::: "memory");
        if (t + 1 < NT) __builtin_amdgcn_s_barrier();

        cur = (cur == 2) ? 0 : cur + 1;
        tgt = (tgt == 2) ? 0 : tgt + 1;
    }

    // ---- combine lane l with l^32 (complementary k rows) ----
    {
        float mo = __shfl(m,  lane ^ 32);
        float Zo = __shfl(Z,  lane ^ 32);
        float No = __shfl(Nm, lane ^ 32);
        float mn = fmaxf(m, mo);
        float ea = ex2(m - mn), eb = ex2(mo - mn);
        float Zc = Z * ea + Zo * eb;
        float Nc = Nm * ea + No * eb;
        if (lhalf == 0) {
            Mg[qs * 32 + l31][ks][0] = mn;
            Mg[qs * 32 + l31][ks][1] = Zc;
            Mg[qs * 32 + l31][ks][2] = Nc;
        }
    }
    __syncthreads();

    // ---- combine the two k-subs, write chunk partial ----
    if (tid < 128) {
        float ma = Mg[tid][0][0], Za = Mg[tid][0][1], Na = Mg[tid][0][2];
        float mb = Mg[tid][1][0], Zb = Mg[tid][1][1], Nb = Mg[tid][1][2];
        float mn = fmaxf(ma, mb);
        float ea = ex2(ma - mn), eb = ex2(mb - mn);
        float* dst = &part_out[((qbase + tid) * 8 + chunk) * 3];
        dst[0] = mn;
        dst[1] = Za * ea + Zb * eb;
        dst[2] = Na * ea + Nb * eb;
    }
}

// ---------------------------------------------------------------- finalize
__global__ void finalize_kernel(const float* __restrict__ part,
                                float* __restrict__ out) {
    __shared__ float red[256];
    int gq = blockIdx.x * 256 + threadIdx.x;
    float contrib = 0.f;
    if (gq < T_ROWS) {
        int nch = (gq < 4096) ? 2 : 8;
        float mm = -INFINITY, zz = 0.f, nn = 0.f;
        for (int c = 0; c < nch; ++c) {
            const float* p = &part[(gq * 8 + c) * 3];
            float mc = p[0], zc = p[1], nc = p[2];
            float mn = fmaxf(mm, mc);
            float s0 = ex2(mm - mn), s1 = ex2(mc - mn);
            zz = zz * s0 + zc * s1;
            nn = nn * s0 + nc * s1;
            mm = mn;
        }
        contrib = nn / zz;
    }
    red[threadIdx.x] = contrib;
    __syncthreads();
    #pragma unroll
    for (int s = 128; s > 0; s >>= 1) {
        if (threadIdx.x < s) red[threadIdx.x] += red[threadIdx.x + s];
        __syncthreads();
    }
    if (threadIdx.x == 0) atomicAdd(out, red[0]);
}

// ----------------------------------------------------------------- launch
extern "C" void kernel_launch(void* const* d_in, const int* in_sizes, int n_in,
                              void* d_out, int out_size, void* d_ws, size_t ws_size,
                              hipStream_t stream) {
    const float* base = (const float*)d_in[0];
    float* out = (float*)d_out;
    float* ws  = (float*)d_ws;

    float*  w      = ws;                        // 10240 f32
    float*  selfs  = ws + T_ROWS;               // 10240 f32
    float*  part   = ws + 2 * T_ROWS;           // 10240*8*3 f32
    __bf16* ksplit = (__bf16*)(ws + 2 * T_ROWS + T_ROWS * 24);  // 10240*128 bf16

    (void)hipMemsetAsync(d_out, 0, sizeof(float), stream);

    prep_kernel<<<T_ROWS / 32, 256, 0, stream>>>(base, ksplit, w, selfs);
    // seg0: 32 qtiles x 2 chunks = 64; seg1: 48 x 8 = 384 -> 448 blocks
    attn_mfma_kernel<<<448, 512, 0, stream>>>(base, ksplit, w, selfs, part);
    finalize_kernel<<<T_ROWS / 256, 256, 0, stream>>>(part, out);
}

// Round 7
// 42.443 us; speedup vs baseline: 1.4582x; 1.0635x over previous
//
#include <hip/hip_runtime.h>
#include <math.h>

// loss = sum_q softmax-weighted avg of w_k, per ragged segment.
//   s2_qk = 1.25*log2(e) * dot(t1[q], t1[k])   (exp2 domain)
//   w_k   = 10 * rowsum(t1[k])
// seg0: q [0,4096),     k [0,2048)
// seg1: q [4096,10240), k [2048,10240)
// R7: barrier-free per-wave streaming. prep writes K (= Q) hi/lo bf16 in
// FRAGMENT-MAJOR layout khi[kt][st][lane][8] so every MFMA A/B fragment is one
// fully-coalesced 1KB global_load_dwordx4 straight to VGPRs. No LDS, no
// __syncthreads in attn. hh-first: 4 MFMA + skip test on hi*hi only; the
// hl+lh correction (and its kl/qlo loads) run only for non-skipped tiles.
// SCALE2 folded post-MFMA (skip threshold pre-divided by SCALE2).

#define T_ROWS 10240
#define SCALE2   1.80336880f   // 1.25 * log2(e)
#define INV_S2   0.55451774f   // 1 / SCALE2
#define SKIP_THR 35.0f

typedef __bf16 bf16x8 __attribute__((ext_vector_type(8)));
typedef float  f32x16 __attribute__((ext_vector_type(16)));
typedef float  f32x4v __attribute__((ext_vector_type(4)));

__device__ __forceinline__ float ex2(float x) {
    return __builtin_amdgcn_exp2f(x);   // v_exp_f32: 2^x, exp2(-inf)=0
}

// ---------------------------------------------------------------- prep
// Frag-major hi/lo split + w + selfs. Thread = (row, 8-dim chunk).
// Fragment layout: khi[kt*2048 + st*512 + lhalf*256 + l31*8], lane = lhalf*32+l31
// holds row 32*kt+l31, dims [st*16 + lhalf*8, +8) — exactly the 32x32x16 A/B frag.
__global__ __launch_bounds__(256)
void prep_kernel(const float* __restrict__ base, __bf16* __restrict__ khi,
                 __bf16* __restrict__ klo, float* __restrict__ w,
                 float* __restrict__ selfs) {
    int tid = threadIdx.x;
    int row = blockIdx.x * 32 + (tid >> 3);
    int c0  = (tid & 7) << 3;
    const float* p = base + (size_t)row * 64 + c0;
    f32x4v a = *(const f32x4v*)p;
    f32x4v b = *(const f32x4v*)(p + 4);

    float sum = ((a[0] + a[1]) + (a[2] + a[3])) + ((b[0] + b[1]) + (b[2] + b[3]));
    float sq = a[0] * a[0];
    sq = fmaf(a[1], a[1], sq); sq = fmaf(a[2], a[2], sq); sq = fmaf(a[3], a[3], sq);
    sq = fmaf(b[0], b[0], sq); sq = fmaf(b[1], b[1], sq);
    sq = fmaf(b[2], b[2], sq); sq = fmaf(b[3], b[3], sq);
    #pragma unroll
    for (int off = 1; off < 8; off <<= 1) {
        sum += __shfl_xor(sum, off);
        sq  += __shfl_xor(sq, off);
    }
    if ((tid & 7) == 0) { w[row] = 10.0f * sum; selfs[row] = SCALE2 * sq; }

    bf16x8 h, l;
    #pragma unroll
    for (int j = 0; j < 4; ++j) {
        __bf16 h0 = (__bf16)a[j];
        h[j] = h0; l[j] = (__bf16)(a[j] - (float)h0);
        __bf16 h1 = (__bf16)b[j];
        h[j + 4] = h1; l[j + 4] = (__bf16)(b[j] - (float)h1);
    }
    int kt = row >> 5, lr = row & 31;
    int st = c0 >> 4, lh = (c0 >> 3) & 1;
    size_t dst = (size_t)kt * 2048 + st * 512 + lh * 256 + lr * 8;
    *(bf16x8*)(khi + dst) = h;
    *(bf16x8*)(klo + dst) = l;
}

// ---------------------------------------------------------------- attn
// One wave = 64 q rows (2 qsubs of 32) x 256 k rows (8 tiles of 32).
// Zero LDS, zero barriers. K prefetched 1 tile ahead into registers.
__global__ __launch_bounds__(256)
void attn_kernel(const __bf16* __restrict__ khi, const __bf16* __restrict__ klo,
                 const float* __restrict__ w, const float* __restrict__ selfs,
                 float* __restrict__ part) {
    const int lane  = threadIdx.x & 63;
    const int l31   = lane & 31;
    const int lhalf = lane >> 5;
    const int wv    = blockIdx.x * 4 + (threadIdx.x >> 6);

    int qb, kt0, chunk; bool sg0;
    if (wv < 512) {            // seg0: 64 q-waves x 8 chunks
        sg0 = true;  qb = (wv >> 3) * 64; chunk = wv & 7; kt0 = chunk * 8;
    } else {                   // seg1: 96 q-waves x 32 chunks
        sg0 = false; int i = wv - 512;
        qb = 4096 + (i >> 5) * 64; chunk = i & 31; kt0 = 64 + chunk * 8;
    }

    // Q hi fragments straight from frag-major storage (unscaled bf16)
    bf16x8 qh[2][4];
    #pragma unroll
    for (int s = 0; s < 2; ++s) {
        const __bf16* qp = khi + (size_t)(qb / 32 + s) * 2048 + lane * 8;
        #pragma unroll
        for (int st = 0; st < 4; ++st) qh[s][st] = *(const bf16x8*)(qp + st * 512);
    }

    float ms[2], Zs[2], Ns[2];
    #pragma unroll
    for (int s = 0; s < 2; ++s) {
        int qrow = qb + s * 32 + l31;
        ms[s] = (sg0 && qrow >= 2048) ? -INFINITY : selfs[qrow];
        Zs[s] = 0.f; Ns[s] = 0.f;
    }

    const __bf16* kp  = khi + (size_t)kt0 * 2048 + lane * 8;
    const __bf16* klp = klo + (size_t)kt0 * 2048 + lane * 8;

    bf16x8 kc[4], kn[4];
    #pragma unroll
    for (int st = 0; st < 4; ++st) kc[st] = *(const bf16x8*)(kp + st * 512);

    #pragma unroll
    for (int t = 0; t < 8; ++t) {
        if (t < 7) {                               // register prefetch, 1 ahead
            #pragma unroll
            for (int st = 0; st < 4; ++st)
                kn[st] = *(const bf16x8*)(kp + (size_t)(t + 1) * 2048 + st * 512);
        }
        #pragma unroll
        for (int s = 0; s < 2; ++s) {
            f32x16 a0;
            #pragma unroll
            for (int r = 0; r < 16; ++r) a0[r] = 0.f;
            #pragma unroll
            for (int st = 0; st < 4; ++st)
                a0 = __builtin_amdgcn_mfma_f32_32x32x16_bf16(kc[st], qh[s][st], a0, 0, 0, 0);

            float h0 = fmaxf(fmaxf(a0[0],  a0[1]),  fmaxf(a0[2],  a0[3]));
            float h1 = fmaxf(fmaxf(a0[4],  a0[5]),  fmaxf(a0[6],  a0[7]));
            float h2 = fmaxf(fmaxf(a0[8],  a0[9]),  fmaxf(a0[10], a0[11]));
            float h3 = fmaxf(fmaxf(a0[12], a0[13]), fmaxf(a0[14], a0[15]));
            float hmax = fmaxf(fmaxf(h0, h1), fmaxf(h2, h3));
            float thr  = (ms[s] - SKIP_THR) * INV_S2;   // raw-score threshold

            if (!__all(hmax <= thr)) {
                // full precision: + kh*qlo + kl*qhi (lazy loads, mostly L1/L2 hot)
                bf16x8 ql[4], kl[4];
                const __bf16* qlp = klo + (size_t)(qb / 32 + s) * 2048 + lane * 8;
                #pragma unroll
                for (int st = 0; st < 4; ++st) {
                    ql[st] = *(const bf16x8*)(qlp + st * 512);
                    kl[st] = *(const bf16x8*)(klp + (size_t)t * 2048 + st * 512);
                }
                f32x16 a1;
                #pragma unroll
                for (int r = 0; r < 16; ++r) a1[r] = 0.f;
                #pragma unroll
                for (int st = 0; st < 4; ++st) {
                    a1 = __builtin_amdgcn_mfma_f32_32x32x16_bf16(kc[st], ql[st], a1, 0, 0, 0);
                    a1 = __builtin_amdgcn_mfma_f32_32x32x16_bf16(kl[st], qh[s][st], a1, 0, 0, 0);
                }
                float s_[16];
                #pragma unroll
                for (int r = 0; r < 16; ++r) s_[r] = (a0[r] + a1[r]) * SCALE2;
                float m0_ = fmaxf(fmaxf(s_[0], s_[4]), fmaxf(s_[8],  s_[12]));
                float m1_ = fmaxf(fmaxf(s_[1], s_[5]), fmaxf(s_[9],  s_[13]));
                float m2_ = fmaxf(fmaxf(s_[2], s_[6]), fmaxf(s_[10], s_[14]));
                float m3_ = fmaxf(fmaxf(s_[3], s_[7]), fmaxf(s_[11], s_[15]));
                float tmax = fmaxf(fmaxf(m0_, m1_), fmaxf(m2_, m3_));
                float mn = fmaxf(ms[s], tmax);
                float sc = ex2(ms[s] - mn);          // exp2(-inf)=0 first time

                const float* wp = w + (kt0 + t) * 32 + lhalf * 4;
                f32x4v wv4[4];
                #pragma unroll
                for (int g = 0; g < 4; ++g) wv4[g] = *(const f32x4v*)(wp + g * 8);

                float z0 = 0.f, z1 = 0.f, z2 = 0.f, z3 = 0.f;
                float n0 = 0.f, n1 = 0.f, n2 = 0.f, n3 = 0.f;
                #pragma unroll
                for (int g = 0; g < 4; ++g) {
                    float e0 = ex2(s_[g * 4]     - mn);
                    float e1 = ex2(s_[g * 4 + 1] - mn);
                    float e2 = ex2(s_[g * 4 + 2] - mn);
                    float e3 = ex2(s_[g * 4 + 3] - mn);
                    z0 += e0; z1 += e1; z2 += e2; z3 += e3;
                    n0 = fmaf(e0, wv4[g][0], n0);
                    n1 = fmaf(e1, wv4[g][1], n1);
                    n2 = fmaf(e2, wv4[g][2], n2);
                    n3 = fmaf(e3, wv4[g][3], n3);
                }
                Zs[s] = fmaf(Zs[s], sc, (z0 + z1) + (z2 + z3));
                Ns[s] = fmaf(Ns[s], sc, (n0 + n1) + (n2 + n3));
                ms[s] = mn;
            }
        }
        if (t < 7) {
            #pragma unroll
            for (int st = 0; st < 4; ++st) kc[st] = kn[st];
        }
    }

    // combine lane l with l^32 (complementary k rows), write chunk partial
    #pragma unroll
    for (int s = 0; s < 2; ++s) {
        float mo = __shfl(ms[s], lane ^ 32);
        float Zo = __shfl(Zs[s], lane ^ 32);
        float No = __shfl(Ns[s], lane ^ 32);
        float mn = fmaxf(ms[s], mo);
        float ea = ex2(ms[s] - mn), eb = ex2(mo - mn);
        if (lhalf == 0) {
            float* dst = &part[((size_t)(qb + s * 32 + l31) * 32 + chunk) * 3];
            dst[0] = mn;
            dst[1] = Zs[s] * ea + Zo * eb;
            dst[2] = Ns[s] * ea + No * eb;
        }
    }
}

// ---------------------------------------------------------------- finalize
__global__ void finalize_kernel(const float* __restrict__ part,
                                float* __restrict__ out) {
    __shared__ float red[256];
    int gq = blockIdx.x * 256 + threadIdx.x;
    float contrib = 0.f;
    if (gq < T_ROWS) {
        int nch = (gq < 4096) ? 8 : 32;
        float mm = -INFINITY, zz = 0.f, nn = 0.f;
        for (int c = 0; c < nch; ++c) {
            const float* p = &part[((size_t)gq * 32 + c) * 3];
            float mc = p[0], zc = p[1], nc = p[2];
            float mn = fmaxf(mm, mc);
            float s0 = ex2(mm - mn), s1 = ex2(mc - mn);
            zz = zz * s0 + zc * s1;
            nn = nn * s0 + nc * s1;
            mm = mn;
        }
        contrib = nn / zz;
    }
    red[threadIdx.x] = contrib;
    __syncthreads();
    #pragma unroll
    for (int s = 128; s > 0; s >>= 1) {
        if (threadIdx.x < s) red[threadIdx.x] += red[threadIdx.x + s];
        __syncthreads();
    }
    if (threadIdx.x == 0) atomicAdd(out, red[0]);
}

// ----------------------------------------------------------------- launch
extern "C" void kernel_launch(void* const* d_in, const int* in_sizes, int n_in,
                              void* d_out, int out_size, void* d_ws, size_t ws_size,
                              hipStream_t stream) {
    const float* base = (const float*)d_in[0];
    float* out = (float*)d_out;
    float* ws  = (float*)d_ws;

    float*  w      = ws;                          // 10240 f32
    float*  selfs  = ws + T_ROWS;                 // 10240 f32
    float*  part   = ws + 2 * T_ROWS;             // 10240*32*3 f32
    __bf16* khi    = (__bf16*)(ws + 2 * T_ROWS + T_ROWS * 96);   // 320*2048 bf16
    __bf16* klo    = khi + 320 * 2048;

    (void)hipMemsetAsync(d_out, 0, sizeof(float), stream);

    prep_kernel<<<T_ROWS / 32, 256, 0, stream>>>(base, khi, klo, w, selfs);
    // 3584 waves = 512 (seg0) + 3072 (seg1); 4 waves/block -> 896 blocks
    attn_kernel<<<896, 256, 0, stream>>>(khi, klo, w, selfs, part);
    finalize_kernel<<<T_ROWS / 256, 256, 0, stream>>>(part, out);
}

// Round 8
// 41.028 us; speedup vs baseline: 1.5085x; 1.0345x over previous
//
#include <hip/hip_runtime.h>
#include <math.h>

// loss = sum_q softmax-weighted avg of w_k, per ragged segment.
//   s2_qk = 1.25*log2(e) * dot(t1[q], t1[k])   (exp2 domain)
//   w_k   = 10 * rowsum(t1[k])
// seg0: q [0,4096),     k [0,2048)
// seg1: q [4096,10240), k [2048,10240)
// R8: barrier-free per-wave streaming (R7 structure) with latency/front-end
// fixes: dynamic outer loop (no 8x unroll -> I$-resident body), correction
// accumulated into a0 (no a1), SCALE2 folded into exp via fmaf, lazy kl/ql
// per tile, <=128 VGPR target (4 waves/SIMD), prep zeroes out (no memset).

#define T_ROWS 10240
#define SCALE2   1.80336880f   // 1.25 * log2(e)
#define INV_S2   0.55451774f   // 1 / SCALE2
#define SKIP_THR 35.0f         // exp2-domain skip margin

typedef __bf16 bf16x8 __attribute__((ext_vector_type(8)));
typedef float  f32x16 __attribute__((ext_vector_type(16)));
typedef float  f32x4v __attribute__((ext_vector_type(4)));

__device__ __forceinline__ float ex2(float x) {
    return __builtin_amdgcn_exp2f(x);   // v_exp_f32: 2^x, exp2(-inf)=0
}

// ---------------------------------------------------------------- prep
// Frag-major hi/lo split + w + selfs. lane=lhalf*32+l31 holds row 32*kt+l31,
// dims [st*16 + lhalf*8, +8): khi[kt*2048 + st*512 + lhalf*256 + l31*8].
__global__ __launch_bounds__(256)
void prep_kernel(const float* __restrict__ base, __bf16* __restrict__ khi,
                 __bf16* __restrict__ klo, float* __restrict__ w,
                 float* __restrict__ selfs, float* __restrict__ out) {
    int tid = threadIdx.x;
    if (blockIdx.x == 0 && tid == 0) *out = 0.f;   // replaces memset dispatch
    int row = blockIdx.x * 32 + (tid >> 3);
    int c0  = (tid & 7) << 3;
    const float* p = base + (size_t)row * 64 + c0;
    f32x4v a = *(const f32x4v*)p;
    f32x4v b = *(const f32x4v*)(p + 4);

    float sum = ((a[0] + a[1]) + (a[2] + a[3])) + ((b[0] + b[1]) + (b[2] + b[3]));
    float sq = a[0] * a[0];
    sq = fmaf(a[1], a[1], sq); sq = fmaf(a[2], a[2], sq); sq = fmaf(a[3], a[3], sq);
    sq = fmaf(b[0], b[0], sq); sq = fmaf(b[1], b[1], sq);
    sq = fmaf(b[2], b[2], sq); sq = fmaf(b[3], b[3], sq);
    #pragma unroll
    for (int off = 1; off < 8; off <<= 1) {
        sum += __shfl_xor(sum, off);
        sq  += __shfl_xor(sq, off);
    }
    if ((tid & 7) == 0) { w[row] = 10.0f * sum; selfs[row] = SCALE2 * sq; }

    bf16x8 h, l;
    #pragma unroll
    for (int j = 0; j < 4; ++j) {
        __bf16 h0 = (__bf16)a[j];
        h[j] = h0; l[j] = (__bf16)(a[j] - (float)h0);
        __bf16 h1 = (__bf16)b[j];
        h[j + 4] = h1; l[j + 4] = (__bf16)(b[j] - (float)h1);
    }
    int kt = row >> 5, lr = row & 31;
    int st = c0 >> 4, lh = (c0 >> 3) & 1;
    size_t dst = (size_t)kt * 2048 + st * 512 + lh * 256 + lr * 8;
    *(bf16x8*)(khi + dst) = h;
    *(bf16x8*)(klo + dst) = l;
}

// ---------------------------------------------------------------- attn
// One wave = 64 q rows (2 qsubs of 32) x 256 k rows (8 tiles of 32).
// Zero LDS, zero barriers. K hi prefetched 1 tile ahead into registers.
__global__ __launch_bounds__(256, 4)
void attn_kernel(const __bf16* __restrict__ khi, const __bf16* __restrict__ klo,
                 const float* __restrict__ w, const float* __restrict__ selfs,
                 float* __restrict__ part) {
    const int lane  = threadIdx.x & 63;
    const int l31   = lane & 31;
    const int lhalf = lane >> 5;
    const int wv    = blockIdx.x * 4 + (threadIdx.x >> 6);

    int qb, kt0, chunk; bool sg0;
    if (wv < 512) {            // seg0: 64 q-waves x 8 chunks
        sg0 = true;  qb = (wv >> 3) * 64; chunk = wv & 7; kt0 = chunk * 8;
    } else {                   // seg1: 96 q-waves x 32 chunks
        sg0 = false; int i = wv - 512;
        qb = 4096 + (i >> 5) * 64; chunk = i & 31; kt0 = 64 + chunk * 8;
    }

    // Q hi fragments (frag-major storage; Q rows = same tensor as K)
    bf16x8 qh[2][4];
    #pragma unroll
    for (int s = 0; s < 2; ++s) {
        const __bf16* qp = khi + (size_t)(qb / 32 + s) * 2048 + lane * 8;
        #pragma unroll
        for (int st = 0; st < 4; ++st) qh[s][st] = *(const bf16x8*)(qp + st * 512);
    }

    float ms[2], Zs[2], Ns[2];
    #pragma unroll
    for (int s = 0; s < 2; ++s) {
        int qrow = qb + s * 32 + l31;
        ms[s] = (sg0 && qrow >= 2048) ? -INFINITY : selfs[qrow];
        Zs[s] = 0.f; Ns[s] = 0.f;
    }

    const __bf16* kp  = khi + (size_t)kt0 * 2048 + lane * 8;
    const __bf16* klp = klo + (size_t)kt0 * 2048 + lane * 8;
    const __bf16* qlo0 = klo + (size_t)(qb / 32) * 2048 + lane * 8;

    bf16x8 kc[4], kn[4];
    #pragma unroll
    for (int st = 0; st < 4; ++st) kc[st] = *(const bf16x8*)(kp + st * 512);

    #pragma unroll 1
    for (int t = 0; t < 8; ++t) {
        if (t < 7) {                               // register prefetch, 1 ahead
            #pragma unroll
            for (int st = 0; st < 4; ++st)
                kn[st] = *(const bf16x8*)(kp + (size_t)(t + 1) * 2048 + st * 512);
        }
        #pragma unroll
        for (int s = 0; s < 2; ++s) {
            f32x16 a0;
            #pragma unroll
            for (int r = 0; r < 16; ++r) a0[r] = 0.f;
            #pragma unroll
            for (int st = 0; st < 4; ++st)
                a0 = __builtin_amdgcn_mfma_f32_32x32x16_bf16(kc[st], qh[s][st], a0, 0, 0, 0);

            // skip test on raw hh scores (threshold pre-divided by SCALE2)
            float h0 = fmaxf(fmaxf(a0[0],  a0[1]),  fmaxf(a0[2],  a0[3]));
            float h1 = fmaxf(fmaxf(a0[4],  a0[5]),  fmaxf(a0[6],  a0[7]));
            float h2 = fmaxf(fmaxf(a0[8],  a0[9]),  fmaxf(a0[10], a0[11]));
            float h3 = fmaxf(fmaxf(a0[12], a0[13]), fmaxf(a0[14], a0[15]));
            float rmax = fmaxf(fmaxf(h0, h1), fmaxf(h2, h3));
            float thr  = (ms[s] - SKIP_THR) * INV_S2;

            if (!__all(rmax <= thr)) {
                // correction accumulates INTO a0: + kh*qlo + kl*qhi
                bf16x8 ql[4], kl[4];
                const __bf16* qlp = qlo0 + (size_t)s * 2048;
                #pragma unroll
                for (int st = 0; st < 4; ++st) {
                    ql[st] = *(const bf16x8*)(qlp + st * 512);
                    kl[st] = *(const bf16x8*)(klp + (size_t)t * 2048 + st * 512);
                }
                #pragma unroll
                for (int st = 0; st < 4; ++st) {
                    a0 = __builtin_amdgcn_mfma_f32_32x32x16_bf16(kc[st], ql[st], a0, 0, 0, 0);
                    a0 = __builtin_amdgcn_mfma_f32_32x32x16_bf16(kl[st], qh[s][st], a0, 0, 0, 0);
                }
                float m0_ = fmaxf(fmaxf(a0[0], a0[4]), fmaxf(a0[8],  a0[12]));
                float m1_ = fmaxf(fmaxf(a0[1], a0[5]), fmaxf(a0[9],  a0[13]));
                float m2_ = fmaxf(fmaxf(a0[2], a0[6]), fmaxf(a0[10], a0[14]));
                float m3_ = fmaxf(fmaxf(a0[3], a0[7]), fmaxf(a0[11], a0[15]));
                float tmax = fmaxf(fmaxf(m0_, m1_), fmaxf(m2_, m3_)) * SCALE2;
                float mn = fmaxf(ms[s], tmax);
                float sc = ex2(ms[s] - mn);          // exp2(-inf)=0 first time

                const float* wp = w + (kt0 + t) * 32 + lhalf * 4;
                f32x4v wv4[4];
                #pragma unroll
                for (int g = 0; g < 4; ++g) wv4[g] = *(const f32x4v*)(wp + g * 8);

                float z0 = 0.f, z1 = 0.f, z2 = 0.f, z3 = 0.f;
                float n0 = 0.f, n1 = 0.f, n2 = 0.f, n3 = 0.f;
                #pragma unroll
                for (int g = 0; g < 4; ++g) {
                    float e0 = ex2(fmaf(a0[g * 4],     SCALE2, -mn));
                    float e1 = ex2(fmaf(a0[g * 4 + 1], SCALE2, -mn));
                    float e2 = ex2(fmaf(a0[g * 4 + 2], SCALE2, -mn));
                    float e3 = ex2(fmaf(a0[g * 4 + 3], SCALE2, -mn));
                    z0 += e0; z1 += e1; z2 += e2; z3 += e3;
                    n0 = fmaf(e0, wv4[g][0], n0);
                    n1 = fmaf(e1, wv4[g][1], n1);
                    n2 = fmaf(e2, wv4[g][2], n2);
                    n3 = fmaf(e3, wv4[g][3], n3);
                }
                Zs[s] = fmaf(Zs[s], sc, (z0 + z1) + (z2 + z3));
                Ns[s] = fmaf(Ns[s], sc, (n0 + n1) + (n2 + n3));
                ms[s] = mn;
            }
        }
        if (t < 7) {
            #pragma unroll
            for (int st = 0; st < 4; ++st) kc[st] = kn[st];
        }
    }

    // combine lane l with l^32 (complementary k rows), write chunk partial
    #pragma unroll
    for (int s = 0; s < 2; ++s) {
        float mo = __shfl(ms[s], lane ^ 32);
        float Zo = __shfl(Zs[s], lane ^ 32);
        float No = __shfl(Ns[s], lane ^ 32);
        float mn = fmaxf(ms[s], mo);
        float ea = ex2(ms[s] - mn), eb = ex2(mo - mn);
        if (lhalf == 0) {
            float* dst = &part[((size_t)(qb + s * 32 + l31) * 32 + chunk) * 3];
            dst[0] = mn;
            dst[1] = Zs[s] * ea + Zo * eb;
            dst[2] = Ns[s] * ea + No * eb;
        }
    }
}

// ---------------------------------------------------------------- finalize
__global__ void finalize_kernel(const float* __restrict__ part,
                                float* __restrict__ out) {
    __shared__ float red[256];
    int gq = blockIdx.x * 256 + threadIdx.x;
    float contrib = 0.f;
    if (gq < T_ROWS) {
        int nch = (gq < 4096) ? 8 : 32;
        float mm = -INFINITY, zz = 0.f, nn = 0.f;
        for (int c = 0; c < nch; ++c) {
            const float* p = &part[((size_t)gq * 32 + c) * 3];
            float mc = p[0], zc = p[1], nc = p[2];
            float mn = fmaxf(mm, mc);
            float s0 = ex2(mm - mn), s1 = ex2(mc - mn);
            zz = zz * s0 + zc * s1;
            nn = nn * s0 + nc * s1;
            mm = mn;
        }
        contrib = nn / zz;
    }
    red[threadIdx.x] = contrib;
    __syncthreads();
    #pragma unroll
    for (int s = 128; s > 0; s >>= 1) {
        if (threadIdx.x < s) red[threadIdx.x] += red[threadIdx.x + s];
        __syncthreads();
    }
    if (threadIdx.x == 0) atomicAdd(out, red[0]);
}

// ----------------------------------------------------------------- launch
extern "C" void kernel_launch(void* const* d_in, const int* in_sizes, int n_in,
                              void* d_out, int out_size, void* d_ws, size_t ws_size,
                              hipStream_t stream) {
    const float* base = (const float*)d_in[0];
    float* out = (float*)d_out;
    float* ws  = (float*)d_ws;

    float*  w      = ws;                          // 10240 f32
    float*  selfs  = ws + T_ROWS;                 // 10240 f32
    float*  part   = ws + 2 * T_ROWS;             // 10240*32*3 f32
    __bf16* khi    = (__bf16*)(ws + 2 * T_ROWS + T_ROWS * 96);   // 320*2048 bf16
    __bf16* klo    = khi + 320 * 2048;

    prep_kernel<<<T_ROWS / 32, 256, 0, stream>>>(base, khi, klo, w, selfs, out);
    // 3584 waves = 512 (seg0) + 3072 (seg1); 4 waves/block -> 896 blocks
    attn_kernel<<<896, 256, 0, stream>>>(khi, klo, w, selfs, part);
    finalize_kernel<<<T_ROWS / 256, 256, 0, stream>>>(part, out);
}